// Round 1
// baseline (586.790 us; speedup 1.0000x reference)
//
#include <hip/hip_runtime.h>

// HardAttention: out[b,c] = sum_t max_s ( xs[b,t,:] . ys[b,c,s,:] )
// B=16, Tx=128, C=64, Ty=128, d=768. fp32 in, fp32 out.
// Strategy: one block per (b,c). 128x128 score tile via bf16 MFMA
// (16x16x32), A from pre-converted bf16 xs in workspace (L2-resident),
// B (ys) streamed fp32 from HBM once, converted inline. Memory-bound,
// floor ~65us (410 MB @ 6.3 TB/s).

typedef __attribute__((ext_vector_type(8))) short short8;   // 8 x bf16 (4 VGPR)
typedef __attribute__((ext_vector_type(4))) float floatx4;  // MFMA acc

#define B_DIM 16
#define TX 128
#define CC 64
#define TY 128
#define DD 768

__device__ __forceinline__ short f2bf(float f) {
  // round-to-nearest-even fp32 -> bf16 (inputs are finite; no NaN handling)
  unsigned u = __builtin_bit_cast(unsigned, f);
  u += 0x7FFFu + ((u >> 16) & 1u);
  return (short)(u >> 16);
}

// ---- pre-pass: convert xs (fp32) -> bf16 into workspace -------------------
__global__ __launch_bounds__(256) void cvt_xs(const float* __restrict__ xs,
                                              short* __restrict__ xb, int n4) {
  int i = blockIdx.x * blockDim.x + threadIdx.x;
  if (i >= n4) return;
  float4 v = reinterpret_cast<const float4*>(xs)[i];
  short4 o;
  o.x = f2bf(v.x);
  o.y = f2bf(v.y);
  o.z = f2bf(v.z);
  o.w = f2bf(v.w);
  reinterpret_cast<short4*>(xb)[i] = o;
}

// ---- main kernel ----------------------------------------------------------
// PRECVT=true : A operand from bf16 workspace copy of xs
// PRECVT=false: A operand loaded fp32 + converted inline (ws too small path)
template <bool PRECVT>
__global__ __launch_bounds__(256, 2) void hardattn(const void* __restrict__ xsv,
                                                   const float* __restrict__ ys,
                                                   float* __restrict__ out) {
  const int blk = blockIdx.x;     // = b*64 + c
  const int b = blk >> 6;
  const int tid = threadIdx.x;
  const int w = tid >> 6;         // wave 0..3 -> s-cols [32w, 32w+32)
  const int lane = tid & 63;
  const int l16 = lane & 15;      // A: row m ; B: row s ; D: col s
  const int kg = lane >> 4;       // input: k-group ; D: row-group

  const float* Bp = ys + (size_t)blk * TY * DD;  // ys[b][c] : [128][768]

  floatx4 acc[8][2];
#pragma unroll
  for (int mt = 0; mt < 8; mt++)
#pragma unroll
    for (int nt = 0; nt < 2; nt++) acc[mt][nt] = (floatx4)0.f;

  // per-lane base pointers
  const short* aBaseH = nullptr;
  const float* aBaseF = nullptr;
  if constexpr (PRECVT) {
    aBaseH = ((const short*)xsv) + (size_t)b * TX * DD + (size_t)l16 * DD + kg * 8;
  } else {
    aBaseF = ((const float*)xsv) + (size_t)b * TX * DD + (size_t)l16 * DD + kg * 8;
  }
  const float* bBase0 = Bp + (size_t)(w * 32 + l16) * DD + kg * 8;
  const float* bBase1 = bBase0 + (size_t)16 * DD;

  for (int k0 = 0; k0 < DD; k0 += 32) {
    // ---- load A fragments (8 m-tiles x 16B/lane) ----
    short8 a[8];
    if constexpr (PRECVT) {
#pragma unroll
      for (int mt = 0; mt < 8; mt++)
        a[mt] = *reinterpret_cast<const short8*>(aBaseH + (size_t)mt * 16 * DD + k0);
    } else {
#pragma unroll
      for (int mt = 0; mt < 8; mt++) {
        const float* p = aBaseF + (size_t)mt * 16 * DD + k0;
        float4 a0 = *reinterpret_cast<const float4*>(p);
        float4 a1 = *reinterpret_cast<const float4*>(p + 4);
        short8 af;
        af[0] = f2bf(a0.x); af[1] = f2bf(a0.y); af[2] = f2bf(a0.z); af[3] = f2bf(a0.w);
        af[4] = f2bf(a1.x); af[5] = f2bf(a1.y); af[6] = f2bf(a1.z); af[7] = f2bf(a1.w);
        a[mt] = af;
      }
    }

    // ---- load B fragments (2 n-tiles x 32B/lane fp32) + convert ----
    float4 b0a = *reinterpret_cast<const float4*>(bBase0 + k0);
    float4 b0b = *reinterpret_cast<const float4*>(bBase0 + k0 + 4);
    float4 b1a = *reinterpret_cast<const float4*>(bBase1 + k0);
    float4 b1b = *reinterpret_cast<const float4*>(bBase1 + k0 + 4);
    short8 bf0, bf1;
    bf0[0] = f2bf(b0a.x); bf0[1] = f2bf(b0a.y); bf0[2] = f2bf(b0a.z); bf0[3] = f2bf(b0a.w);
    bf0[4] = f2bf(b0b.x); bf0[5] = f2bf(b0b.y); bf0[6] = f2bf(b0b.z); bf0[7] = f2bf(b0b.w);
    bf1[0] = f2bf(b1a.x); bf1[1] = f2bf(b1a.y); bf1[2] = f2bf(b1a.z); bf1[3] = f2bf(b1a.w);
    bf1[4] = f2bf(b1b.x); bf1[5] = f2bf(b1b.y); bf1[6] = f2bf(b1b.z); bf1[7] = f2bf(b1b.w);

    // ---- MFMA: D[row = m][col = s] ----
#pragma unroll
    for (int mt = 0; mt < 8; mt++) {
      acc[mt][0] = __builtin_amdgcn_mfma_f32_16x16x32_bf16(a[mt], bf0, acc[mt][0], 0, 0, 0);
      acc[mt][1] = __builtin_amdgcn_mfma_f32_16x16x32_bf16(a[mt], bf1, acc[mt][1], 0, 0, 0);
    }
  }

  // ---- epilogue: max over s (cols), then sum over t (rows) ----
  // C/D layout (verified m89/m91): col = lane&15, row = (lane>>4)*4 + reg
  __shared__ float part[4][TX];  // per-wave per-row max over its 32 cols
  __shared__ float wsum[2];

#pragma unroll
  for (int mt = 0; mt < 8; mt++) {
#pragma unroll
    for (int r = 0; r < 4; r++) {
      float v = fmaxf(acc[mt][0][r], acc[mt][1][r]);
      // max across the 16 column-lanes (masks < 16 stay in the group)
      v = fmaxf(v, __shfl_xor(v, 1, 64));
      v = fmaxf(v, __shfl_xor(v, 2, 64));
      v = fmaxf(v, __shfl_xor(v, 4, 64));
      v = fmaxf(v, __shfl_xor(v, 8, 64));
      if (l16 == 0) part[w][mt * 16 + kg * 4 + r] = v;
    }
  }
  __syncthreads();

  if (tid < 128) {
    float rm = fmaxf(fmaxf(part[0][tid], part[1][tid]),
                     fmaxf(part[2][tid], part[3][tid]));
    float s = rm;
    s += __shfl_down(s, 32, 64);
    s += __shfl_down(s, 16, 64);
    s += __shfl_down(s, 8, 64);
    s += __shfl_down(s, 4, 64);
    s += __shfl_down(s, 2, 64);
    s += __shfl_down(s, 1, 64);
    if (lane == 0) wsum[w] = s;
  }
  __syncthreads();
  if (tid == 0) out[blk] = wsum[0] + wsum[1];
}

extern "C" void kernel_launch(void* const* d_in, const int* in_sizes, int n_in,
                              void* d_out, int out_size, void* d_ws, size_t ws_size,
                              hipStream_t stream) {
  const float* xs = (const float*)d_in[0];  // (16,128,768)
  const float* ys = (const float*)d_in[1];  // (16,64,128,768)
  float* out = (float*)d_out;               // (16,64)

  const size_t xs_elems = (size_t)B_DIM * TX * DD;  // 1,572,864
  const size_t need = xs_elems * sizeof(short);     // 3,145,728 B

  if (ws_size >= need) {
    short* xb = (short*)d_ws;
    int n4 = (int)(xs_elems / 4);  // 393,216 float4 groups
    cvt_xs<<<(n4 + 255) / 256, 256, 0, stream>>>(xs, xb, n4);
    hardattn<true><<<B_DIM * CC, 256, 0, stream>>>((const void*)xb, ys, out);
  } else {
    hardattn<false><<<B_DIM * CC, 256, 0, stream>>>((const void*)xs, ys, out);
  }
}